// Round 6
// baseline (159.622 us; speedup 1.0000x reference)
//
#include <hip/hip_runtime.h>
#include <math.h>

#define HW 2304           // 48*48
#define O192 192
#define SCALE_F 0.35355339059327373f   // 8^-0.5

typedef unsigned int u32;
typedef __attribute__((address_space(1))) const u32 gu32;
typedef __attribute__((address_space(3))) u32 lu32;
// async global->LDS DMA, 16B per lane; LDS dest = wave-uniform base + lane*16
__device__ __forceinline__ void dma16(const void* g, void* l) {
  __builtin_amdgcn_global_load_lds((gu32*)g, (lu32*)l, 16, 0, 0);
}

// ---------------- Kernel A: 1x1 conv -> q,k (QKV) and v (V2) ----------------
__global__ __launch_bounds__(256) void qkv_kernel(
    const float* __restrict__ F, const float* __restrict__ W,
    float* __restrict__ QKV, float* __restrict__ V2) {
  __shared__ __align__(16) float sW[384];   // two o0 sets x {q,k,v} rows x 64
  int blk = blockIdx.x;
  int idx0 = blk * 256;
  int r0 = idx0 / HW;
  int r1 = (idx0 + 255) / HW;
  int tid = threadIdx.x;
  if (tid < 192) {
    int g = tid >> 6, c = tid & 63;
    sW[tid]       = W[((r0 & 63) + g * 64) * 64 + c];
    sW[192 + tid] = W[((r1 & 63) + g * 64) * 64 + c];
  }
  __syncthreads();
  int idx = idx0 + tid;
  int p  = idx % HW;
  int r  = idx / HW;
  int o0 = r & 63;
  int b  = r >> 6;
  const float4* w4 = (const float4*)(sW + ((r == r0) ? 0 : 192));
  const float* f = F + (b * 64) * HW + p;
  float aq = 0.f, ak = 0.f, av = 0.f;
  #pragma unroll 4
  for (int c4 = 0; c4 < 16; c4++) {
    float4 wq = w4[c4];
    float4 wk = w4[16 + c4];
    float4 wv = w4[32 + c4];
    float f0 = f[(c4 * 4 + 0) * HW];
    float f1 = f[(c4 * 4 + 1) * HW];
    float f2 = f[(c4 * 4 + 2) * HW];
    float f3 = f[(c4 * 4 + 3) * HW];
    aq = fmaf(wq.x, f0, aq); ak = fmaf(wk.x, f0, ak); av = fmaf(wv.x, f0, av);
    aq = fmaf(wq.y, f1, aq); ak = fmaf(wk.y, f1, ak); av = fmaf(wv.y, f1, av);
    aq = fmaf(wq.z, f2, aq); ak = fmaf(wk.z, f2, ak); av = fmaf(wv.z, f2, av);
    aq = fmaf(wq.w, f3, aq); ak = fmaf(wk.w, f3, ak); av = fmaf(wv.w, f3, av);
  }
  float* qp = QKV + (b * HW + p) * O192;
  qp[o0]      = aq;
  qp[o0 + 64] = ak;
  V2[(((b << 3) + (o0 >> 3)) * HW + p) * 8 + (o0 & 7)] = av;
}

// ---------------- Kernel B: 11x11 stride-8 conv + bias + exact GELU ----------
__global__ __launch_bounds__(256) void conv_kernel(
    const float* __restrict__ QKV, const float* __restrict__ Wq,
    const float* __restrict__ Bq, const float* __restrict__ Wk,
    const float* __restrict__ Bk, float* __restrict__ QD) {
  __shared__ float sW[7744];
  __shared__ float sRed[4 * 64 * 6];
  int blk = blockIdx.x;
  int xcd = blk & 7;
  int T = xcd >> 2, b = (xcd >> 1) & 1, s = xcd & 1;
  int idx = (blk >> 3) * 2 + s;
  int o  = idx / 6;
  int oy = idx % 6;
  const float* Wg = T ? Wk : Wq;
  for (int i = threadIdx.x; i < 7744; i += 256) sW[i] = Wg[o * 7744 + i];
  __syncthreads();
  int wv = threadIdx.x >> 6;
  int c  = threadIdx.x & 63;
  const float* base = QKV + b * (HW * O192) + T * 64 + c;
  float acc[6];
  #pragma unroll
  for (int ox = 0; ox < 6; ox++) acc[ox] = 0.f;
  for (int kyi = 0; kyi < 3; kyi++) {
    int ky = wv * 3 + kyi;
    if (ky > 10) break;
    int y = oy * 8 - 2 + ky;
    if ((unsigned)y < 48u) {
      float xrow[48];
      #pragma unroll
      for (int x = 0; x < 48; x++) xrow[x] = base[(y * 48 + x) * O192];
      #pragma unroll
      for (int kx = 0; kx < 11; kx++) {
        float wt = sW[c * 121 + ky * 11 + kx];
        #pragma unroll
        for (int ox = 0; ox < 6; ox++) {
          int x = ox * 8 - 2 + kx;
          if (x >= 0 && x < 48) acc[ox] = fmaf(xrow[x], wt, acc[ox]);
        }
      }
    }
  }
  #pragma unroll
  for (int ox = 0; ox < 6; ox++) sRed[(wv * 64 + c) * 6 + ox] = acc[ox];
  __syncthreads();
  if (threadIdx.x < 64) {
    int t = threadIdx.x;
    float r[6];
    #pragma unroll
    for (int ox = 0; ox < 6; ox++)
      r[ox] = sRed[t * 6 + ox] + sRed[(64 + t) * 6 + ox]
            + sRed[(128 + t) * 6 + ox] + sRed[(192 + t) * 6 + ox];
    #pragma unroll
    for (int off = 32; off; off >>= 1) {
      #pragma unroll
      for (int ox = 0; ox < 6; ox++) r[ox] += __shfl_down(r[ox], off, 64);
    }
    if (t == 0) {
      float bias = T ? Bk[o] : Bq[o];
      #pragma unroll
      for (int ox = 0; ox < 6; ox++) {
        float g = r[ox] + bias;
        float ge = 0.5f * g * (1.0f + erff(g * 0.70710678118654752f));
        QD[((T * 2 + b) * 64 + o) * 36 + oy * 6 + ox] = ge;
      }
    }
  }
}

// ---------------- Kernel D: factored attention v6 ---------------------------
// 288 blocks = (bh = blk%16 [XCD-local], Ipair = blk/16).  128 rows (2 I),
// ALL 2304 j in-block -> direct out write.  8 waves; wave w owns jx
// [6w,6w+6) x all 48 jy.  Lane = (l32 row-slot, chalf channel-half); each
// lane covers rows {k8*32+l32, k8<4} x 4 channels -> one b128 V read per
// (wave,j) serves 128 rows.  All LDS layouts dense 16B/lane (slot-permuted
// sQ, eA[jy][slot]) -> zero bank conflicts.  V staged in 4 quarters via DMA.
#define OFF_V    0        // 4608 f : V quarter [12jy][48jx][8c]
#define OFF_QLO  4608     // 512  f : q[0:4] by slot = (row&31)*4 + (row>>5)
#define OFF_QHI  5120     // 512  f : q[4:8] by slot
#define OFF_EA   5632     // 6144 f : eA [jy48][slot128]; union sRed (2560) after
#define OFF_PHT  11776    // 384  f
#define OFF_PWT  12160    // 384  f
#define OFF_E    12544    // 72   f : E [Ik2][J36]
#define OFF_Z    12616    // 32   f
#define SBUF_N   12648    // 50.6 KB

__global__ __launch_bounds__(512) void attn_kernel(
    const float* __restrict__ QKV, const float* __restrict__ V2,
    const float* __restrict__ QD, const float* __restrict__ PH,
    const float* __restrict__ PW, float* __restrict__ out) {
  __shared__ __align__(16) float sB[SBUF_N];
  int blk = blockIdx.x;
  int bh = blk & 15;            // same bh -> same XCD slot pattern
  int Ip = blk >> 4;            // 0..17
  int b = bh >> 3, h = bh & 7;
  int r0 = Ip * 128;
  int tid = threadIdx.x;
  int w = tid >> 6, lane = tid & 63;
  int l32 = lane & 31, chalf = lane >> 5;
  // ---- stage small tables ----
  if (tid < 384) {
    sB[OFF_PHT + tid] = PH[(tid & 7) * 48 + (tid >> 3)];
    sB[OFF_PWT + tid] = PW[(tid & 7) * 48 + (tid >> 3)];
  }
  if (tid < 72) {   // fused dots: E[Ik][J] = exp(scale * qd_I . kd_J)
    int Ik = tid / 36, J = tid - Ik * 36;
    const float* qd = QD + ((0 + b) * 64 + h * 8) * 36 + (Ip * 2 + Ik);
    const float* kd = QD + ((2 + b) * 64 + h * 8) * 36 + J;
    float acc = 0.f;
    #pragma unroll
    for (int c8 = 0; c8 < 8; c8++) acc = fmaf(qd[c8 * 36], kd[c8 * 36], acc);
    sB[OFF_E + tid] = __expf(SCALE_F * acc);
  }
  if (tid < 256) {  // q rows, slot-permuted so eB reads are dense b128
    int row = tid >> 1, half = tid & 1;
    int slot = (row & 31) * 4 + (row >> 5);
    float4 qv = *(const float4*)(QKV + (b * HW + r0 + row) * O192 + h * 8 + half * 4);
    *(float4*)(sB + (half ? OFF_QHI : OFF_QLO) + slot * 4) = qv;
  }
  __syncthreads();
  // ---- eA table: eA[jy][slot] = exp(q_row(slot) . PH[:,jy]) ----
  #pragma unroll
  for (int m = 0; m < 12; m++) {
    int flat = tid + m * 512;           // jy*128 + slot
    int jy = flat >> 7, s = flat & 127;
    float4 qa = *(const float4*)(sB + OFF_QLO + s * 4);   // dense 16B/lane
    float4 qb = *(const float4*)(sB + OFF_QHI + s * 4);
    const float* pp = sB + OFF_PHT + jy * 8;              // half-wave uniform
    float d = qa.x*pp[0]+qa.y*pp[1]+qa.z*pp[2]+qa.w*pp[3]
            + qb.x*pp[4]+qb.y*pp[5]+qb.z*pp[6]+qb.w*pp[7];
    sB[OFF_EA + flat] = __expf(d);                        // dense write
  }
  // ---- eB regs: 4 rows x this wave's 6 jx ----
  float eB[4][6];
  #pragma unroll
  for (int k8 = 0; k8 < 4; k8++) {
    float4 qa = *(const float4*)(sB + OFF_QLO + (l32 * 4 + k8) * 4);  // dense
    float4 qb = *(const float4*)(sB + OFF_QHI + (l32 * 4 + k8) * 4);
    #pragma unroll
    for (int i = 0; i < 6; i++) {
      const float* pp = sB + OFF_PWT + (w * 6 + i) * 8;   // wave-uniform
      float d = qa.x*pp[0]+qa.y*pp[1]+qa.z*pp[2]+qa.w*pp[3]
              + qb.x*pp[4]+qb.y*pp[5]+qb.z*pp[6]+qb.w*pp[7];
      eB[k8][i] = __expf(d);
    }
  }
  float accv[4][4], zz[4];
  #pragma unroll
  for (int k8 = 0; k8 < 4; k8++) {
    zz[k8] = 0.f;
    #pragma unroll
    for (int c = 0; c < 4; c++) accv[k8][c] = 0.f;
  }
  // ---- main loop: 4 V quarters of 12 jy ----
  const float4* sV4 = (const float4*)(sB + OFF_V);
  for (int p = 0; p < 4; p++) {
    __syncthreads();   // prev-phase reads done; (p=0) prologue writes visible
    {
      const char* src = (const char*)(V2 + (size_t)bh * (HW * 8) + p * 4608);
      for (int m = w; m < 18; m += 8)
        dma16(src + m * 1024 + lane * 16, (char*)(sB + OFF_V) + m * 1024);
    }
    __syncthreads();   // vmcnt drained before barrier -> V visible
    #pragma unroll
    for (int jyL = 0; jyL < 12; jyL++) {
      int jy = p * 12 + jyL;
      float4 ea = *(const float4*)(sB + OFF_EA + jy * 128 + l32 * 4);  // dense
      int cb = jy * 48 + w * 6;               // global j at i=0 (wave-uniform)
      int J0 = cb >> 6, J1 = (cb + 5) >> 6;
      int ib = 64 - (cb & 63);                // i >= ib uses J1 (wave-uniform)
      float e00 = sB[OFF_E + J0], e01 = sB[OFF_E + 36 + J0];
      float e10 = sB[OFF_E + J1], e11 = sB[OFF_E + 36 + J1];
      float a0[4], a1[4];
      a0[0] = ea.x * e00; a0[1] = ea.y * e00;   // k8 0,1 -> rows 0..63 -> I0
      a0[2] = ea.z * e01; a0[3] = ea.w * e01;   // k8 2,3 -> rows 64..127 -> I1
      a1[0] = ea.x * e10; a1[1] = ea.y * e10;
      a1[2] = ea.z * e11; a1[3] = ea.w * e11;
      #pragma unroll
      for (int i = 0; i < 6; i++) {
        float4 v = sV4[(jyL * 48 + w * 6 + i) * 2 + chalf];  // broadcast
        bool s0 = (i < ib);                   // wave-uniform select
        #pragma unroll
        for (int k8 = 0; k8 < 4; k8++) {
          float wgt = (s0 ? a0[k8] : a1[k8]) * eB[k8][i];
          accv[k8][0] = fmaf(wgt, v.x, accv[k8][0]);
          accv[k8][1] = fmaf(wgt, v.y, accv[k8][1]);
          accv[k8][2] = fmaf(wgt, v.z, accv[k8][2]);
          accv[k8][3] = fmaf(wgt, v.w, accv[k8][3]);
          zz[k8] += wgt;
        }
      }
    }
  }
  // ---- epilogue: per k8 group (32 rows), cross-wave reduce + normalize ----
  float* sU = sB + OFF_EA;    // eA dead; 2560 <= 6144
  #pragma unroll
  for (int k8 = 0; k8 < 4; k8++) {
    __syncthreads();
    {
      float* rp = sU + (w * 64 + lane) * 5;   // stride-5: conflict-free b32
      rp[0] = accv[k8][0]; rp[1] = accv[k8][1];
      rp[2] = accv[k8][2]; rp[3] = accv[k8][3];
      rp[4] = zz[k8];
    }
    __syncthreads();
    if (tid < 32) {      // Z: both chalf halves counted -> invz = 2/sum
      float z = 0.f;
      #pragma unroll
      for (int ww = 0; ww < 8; ww++)
        z += sU[(ww * 64 + tid) * 5 + 4] + sU[(ww * 64 + 32 + tid) * 5 + 4];
      sB[OFF_Z + tid] = 2.0f / z;
    }
    __syncthreads();
    if (tid < 256) {
      int row32 = tid & 31, c = tid >> 5;     // c 0..7
      int ln = ((c >> 2) << 5) + row32;       // chalf group holding channel c
      float num = 0.f;
      #pragma unroll
      for (int ww = 0; ww < 8; ww++) num += sU[(ww * 64 + ln) * 5 + (c & 3)];
      out[(b * 64 + h * 8 + c) * HW + r0 + k8 * 32 + row32] =
          num * sB[OFF_Z + row32];
    }
  }
}

extern "C" void kernel_launch(void* const* d_in, const int* in_sizes, int n_in,
                              void* d_out, int out_size, void* d_ws, size_t ws_size,
                              hipStream_t stream) {
  const float* F    = (const float*)d_in[0];
  const float* Wqkv = (const float*)d_in[1];
  const float* Wq   = (const float*)d_in[2];
  const float* Bq   = (const float*)d_in[3];
  const float* Wk   = (const float*)d_in[4];
  const float* Bk   = (const float*)d_in[5];
  const float* PH   = (const float*)d_in[6];
  const float* PW   = (const float*)d_in[7];
  float* out = (float*)d_out;

  float* ws  = (float*)d_ws;
  float* QKV = ws;                        // 884736 f
  float* V2  = QKV + 2 * HW * O192;       // 294912 f
  float* QD  = V2 + 2 * 8 * HW * 8;       // 9216 f

  qkv_kernel <<<1152, 256, 0, stream>>>(F, Wqkv, QKV, V2);
  conv_kernel<<<1536, 256, 0, stream>>>(QKV, Wq, Bq, Wk, Bk, QD);
  attn_kernel<<<288,  512, 0, stream>>>(QKV, V2, QD, PH, PW, out);
}

// Round 7
// 153.842 us; speedup vs baseline: 1.0376x; 1.0376x over previous
//
#include <hip/hip_runtime.h>
#include <math.h>

#define HW 2304           // 48*48
#define O192 192
#define SCALE_F 0.35355339059327373f   // 8^-0.5

typedef unsigned int u32;
typedef __attribute__((address_space(1))) const u32 gu32;
typedef __attribute__((address_space(3))) u32 lu32;
// async global->LDS DMA, 16B per lane; LDS dest = wave-uniform base + lane*16
__device__ __forceinline__ void dma16(const void* g, void* l) {
  __builtin_amdgcn_global_load_lds((gu32*)g, (lu32*)l, 16, 0, 0);
}

// ---------------- Kernel A: 1x1 conv -> q,k (QKV) and v (V2) ----------------
__global__ __launch_bounds__(256) void qkv_kernel(
    const float* __restrict__ F, const float* __restrict__ W,
    float* __restrict__ QKV, float* __restrict__ V2) {
  __shared__ __align__(16) float sW[384];   // two o0 sets x {q,k,v} rows x 64
  int blk = blockIdx.x;
  int idx0 = blk * 256;
  int r0 = idx0 / HW;
  int r1 = (idx0 + 255) / HW;
  int tid = threadIdx.x;
  if (tid < 192) {
    int g = tid >> 6, c = tid & 63;
    sW[tid]       = W[((r0 & 63) + g * 64) * 64 + c];
    sW[192 + tid] = W[((r1 & 63) + g * 64) * 64 + c];
  }
  __syncthreads();
  int idx = idx0 + tid;
  int p  = idx % HW;
  int r  = idx / HW;
  int o0 = r & 63;
  int b  = r >> 6;
  const float4* w4 = (const float4*)(sW + ((r == r0) ? 0 : 192));
  const float* f = F + (b * 64) * HW + p;
  float aq = 0.f, ak = 0.f, av = 0.f;
  #pragma unroll 4
  for (int c4 = 0; c4 < 16; c4++) {
    float4 wq = w4[c4];
    float4 wk = w4[16 + c4];
    float4 wv = w4[32 + c4];
    float f0 = f[(c4 * 4 + 0) * HW];
    float f1 = f[(c4 * 4 + 1) * HW];
    float f2 = f[(c4 * 4 + 2) * HW];
    float f3 = f[(c4 * 4 + 3) * HW];
    aq = fmaf(wq.x, f0, aq); ak = fmaf(wk.x, f0, ak); av = fmaf(wv.x, f0, av);
    aq = fmaf(wq.y, f1, aq); ak = fmaf(wk.y, f1, ak); av = fmaf(wv.y, f1, av);
    aq = fmaf(wq.z, f2, aq); ak = fmaf(wk.z, f2, ak); av = fmaf(wv.z, f2, av);
    aq = fmaf(wq.w, f3, aq); ak = fmaf(wk.w, f3, ak); av = fmaf(wv.w, f3, av);
  }
  float* qp = QKV + (b * HW + p) * O192;
  qp[o0]      = aq;
  qp[o0 + 64] = ak;
  V2[(((b << 3) + (o0 >> 3)) * HW + p) * 8 + (o0 & 7)] = av;
}

// ---------------- Kernel B: 11x11 stride-8 conv + bias + exact GELU ----------
__global__ __launch_bounds__(256) void conv_kernel(
    const float* __restrict__ QKV, const float* __restrict__ Wq,
    const float* __restrict__ Bq, const float* __restrict__ Wk,
    const float* __restrict__ Bk, float* __restrict__ QD) {
  __shared__ float sW[7744];
  __shared__ float sRed[4 * 64 * 6];
  int blk = blockIdx.x;
  int xcd = blk & 7;
  int T = xcd >> 2, b = (xcd >> 1) & 1, s = xcd & 1;
  int idx = (blk >> 3) * 2 + s;
  int o  = idx / 6;
  int oy = idx % 6;
  const float* Wg = T ? Wk : Wq;
  for (int i = threadIdx.x; i < 7744; i += 256) sW[i] = Wg[o * 7744 + i];
  __syncthreads();
  int wv = threadIdx.x >> 6;
  int c  = threadIdx.x & 63;
  const float* base = QKV + b * (HW * O192) + T * 64 + c;
  float acc[6];
  #pragma unroll
  for (int ox = 0; ox < 6; ox++) acc[ox] = 0.f;
  for (int kyi = 0; kyi < 3; kyi++) {
    int ky = wv * 3 + kyi;
    if (ky > 10) break;
    int y = oy * 8 - 2 + ky;
    if ((unsigned)y < 48u) {
      float xrow[48];
      #pragma unroll
      for (int x = 0; x < 48; x++) xrow[x] = base[(y * 48 + x) * O192];
      #pragma unroll
      for (int kx = 0; kx < 11; kx++) {
        float wt = sW[c * 121 + ky * 11 + kx];
        #pragma unroll
        for (int ox = 0; ox < 6; ox++) {
          int x = ox * 8 - 2 + kx;
          if (x >= 0 && x < 48) acc[ox] = fmaf(xrow[x], wt, acc[ox]);
        }
      }
    }
  }
  #pragma unroll
  for (int ox = 0; ox < 6; ox++) sRed[(wv * 64 + c) * 6 + ox] = acc[ox];
  __syncthreads();
  if (threadIdx.x < 64) {
    int t = threadIdx.x;
    float r[6];
    #pragma unroll
    for (int ox = 0; ox < 6; ox++)
      r[ox] = sRed[t * 6 + ox] + sRed[(64 + t) * 6 + ox]
            + sRed[(128 + t) * 6 + ox] + sRed[(192 + t) * 6 + ox];
    #pragma unroll
    for (int off = 32; off; off >>= 1) {
      #pragma unroll
      for (int ox = 0; ox < 6; ox++) r[ox] += __shfl_down(r[ox], off, 64);
    }
    if (t == 0) {
      float bias = T ? Bk[o] : Bq[o];
      #pragma unroll
      for (int ox = 0; ox < 6; ox++) {
        float g = r[ox] + bias;
        float ge = 0.5f * g * (1.0f + erff(g * 0.70710678118654752f));
        QD[((T * 2 + b) * 64 + o) * 36 + oy * 6 + ox] = ge;
      }
    }
  }
}

// ---------------- Kernel D: factored attention v7 (j-split x2) --------------
// 576 blocks = (bh = blk%16 [XCD-local], jh = (blk>>4)&1, Ip = blk>>5).
// 128 rows x 1152 j per block.  8 waves; wave w owns jx [6w,6w+6) x 24 jy.
// Lane = (l32 row-slot, chalf channel-half); 4 rows/lane x 4 channels ->
// one b128 V read per (wave,j) serves 128 rows.  Dense conflict-free LDS.
// Partial num/Z -> workspace; combine_kernel merges 2 j-halves.
#define OFF_V    0        // 4608 f : V quarter [12jy][48jx][8c]
#define OFF_QLO  4608     // 512  f : q[0:4] by slot = (row&31)*4 + (row>>5)
#define OFF_QHI  5120     // 512  f : q[4:8] by slot
#define OFF_EA   5632     // 3072 f : eA [jyRel24][slot128]; union sRed (2560)
#define OFF_PHT  8704     // 192  f : PH^T for this half's 24 jy
#define OFF_PWT  8896     // 384  f
#define OFF_E    9280     // 72   f : E [Ik2][J36]
#define OFF_Z    9352     // 32   f
#define SBUF_N   9384     // 37.5 KB -> 4 blocks/CU by LDS

__global__ __launch_bounds__(512) void attn_kernel(
    const float* __restrict__ QKV, const float* __restrict__ V2,
    const float* __restrict__ QD, const float* __restrict__ PH,
    const float* __restrict__ PW, float* __restrict__ Pnum,
    float* __restrict__ PZ) {
  __shared__ __align__(16) float sB[SBUF_N];
  int blk = blockIdx.x;
  int bh = blk & 15;            // same bh clusters on one XCD slot
  int jh = (blk >> 4) & 1;      // j half
  int Ip = blk >> 5;            // 0..17
  int b = bh >> 3, h = bh & 7;
  int r0 = Ip * 128;
  int tid = threadIdx.x;
  int w = tid >> 6, lane = tid & 63;
  int l32 = lane & 31, chalf = lane >> 5;
  // ---- stage small tables ----
  if (tid < 192) {              // PH^T for jy in [jh*24, jh*24+24)
    sB[OFF_PHT + tid] = PH[(tid & 7) * 48 + jh * 24 + (tid >> 3)];
  } else {                      // PW^T [0..320)
    int i = tid - 192;
    sB[OFF_PWT + i] = PW[(i & 7) * 48 + (i >> 3)];
  }
  if (tid < 64) {               // PW^T [320..384)
    int i = 320 + tid;
    sB[OFF_PWT + i] = PW[(i & 7) * 48 + (i >> 3)];
  }
  if (tid < 72) {   // fused dots: E[Ik][J] = exp(scale * qd_I . kd_J)
    int Ik = tid / 36, J = tid - Ik * 36;
    const float* qd = QD + ((0 + b) * 64 + h * 8) * 36 + (Ip * 2 + Ik);
    const float* kd = QD + ((2 + b) * 64 + h * 8) * 36 + J;
    float acc = 0.f;
    #pragma unroll
    for (int c8 = 0; c8 < 8; c8++) acc = fmaf(qd[c8 * 36], kd[c8 * 36], acc);
    sB[OFF_E + tid] = __expf(SCALE_F * acc);
  }
  if (tid < 256) {  // q rows, slot-permuted so eB reads are dense b128
    int row = tid >> 1, half = tid & 1;
    int slot = (row & 31) * 4 + (row >> 5);
    float4 qv = *(const float4*)(QKV + (b * HW + r0 + row) * O192 + h * 8 + half * 4);
    *(float4*)(sB + (half ? OFF_QHI : OFF_QLO) + slot * 4) = qv;
  }
  __syncthreads();
  // ---- eA table: eA[jyRel][slot] = exp(q_row(slot) . PH[:,jy]) ----
  #pragma unroll
  for (int m = 0; m < 6; m++) {
    int flat = tid + m * 512;           // jyRel*128 + slot
    int jyRel = flat >> 7, s = flat & 127;
    float4 qa = *(const float4*)(sB + OFF_QLO + s * 4);   // dense 16B/lane
    float4 qb = *(const float4*)(sB + OFF_QHI + s * 4);
    const float* pp = sB + OFF_PHT + jyRel * 8;
    float d = qa.x*pp[0]+qa.y*pp[1]+qa.z*pp[2]+qa.w*pp[3]
            + qb.x*pp[4]+qb.y*pp[5]+qb.z*pp[6]+qb.w*pp[7];
    sB[OFF_EA + flat] = __expf(d);
  }
  // ---- eB regs: 4 rows x this wave's 6 jx ----
  float eB[4][6];
  #pragma unroll
  for (int k8 = 0; k8 < 4; k8++) {
    float4 qa = *(const float4*)(sB + OFF_QLO + (l32 * 4 + k8) * 4);
    float4 qb = *(const float4*)(sB + OFF_QHI + (l32 * 4 + k8) * 4);
    #pragma unroll
    for (int i = 0; i < 6; i++) {
      const float* pp = sB + OFF_PWT + (w * 6 + i) * 8;   // wave-uniform
      float d = qa.x*pp[0]+qa.y*pp[1]+qa.z*pp[2]+qa.w*pp[3]
              + qb.x*pp[4]+qb.y*pp[5]+qb.z*pp[6]+qb.w*pp[7];
      eB[k8][i] = __expf(d);
    }
  }
  float accv[4][4], zz[4];
  #pragma unroll
  for (int k8 = 0; k8 < 4; k8++) {
    zz[k8] = 0.f;
    #pragma unroll
    for (int c = 0; c < 4; c++) accv[k8][c] = 0.f;
  }
  // ---- main loop: this half's 2 V quarters of 12 jy ----
  const float4* sV4 = (const float4*)(sB + OFF_V);
  for (int p = 0; p < 2; p++) {
    int pq = jh * 2 + p;
    __syncthreads();
    {
      const char* src = (const char*)(V2 + (size_t)bh * (HW * 8) + pq * 4608);
      for (int m = w; m < 18; m += 8)
        dma16(src + m * 1024 + lane * 16, (char*)(sB + OFF_V) + m * 1024);
    }
    __syncthreads();
    #pragma unroll
    for (int jyL = 0; jyL < 12; jyL++) {
      int jyRel = p * 12 + jyL;
      int jy = jh * 24 + jyRel;
      float4 ea = *(const float4*)(sB + OFF_EA + jyRel * 128 + l32 * 4);
      int cb = jy * 48 + w * 6;               // global j at i=0 (wave-uniform)
      int J0 = cb >> 6, J1 = (cb + 5) >> 6;
      int ib = 64 - (cb & 63);                // i >= ib uses J1 (wave-uniform)
      float e00 = sB[OFF_E + J0], e01 = sB[OFF_E + 36 + J0];
      float e10 = sB[OFF_E + J1], e11 = sB[OFF_E + 36 + J1];
      float a0[4], a1[4];
      a0[0] = ea.x * e00; a0[1] = ea.y * e00;   // k8 0,1 -> rows 0..63 -> I0
      a0[2] = ea.z * e01; a0[3] = ea.w * e01;   // k8 2,3 -> rows 64..127 -> I1
      a1[0] = ea.x * e10; a1[1] = ea.y * e10;
      a1[2] = ea.z * e11; a1[3] = ea.w * e11;
      #pragma unroll
      for (int i = 0; i < 6; i++) {
        float4 v = sV4[(jyL * 48 + w * 6 + i) * 2 + chalf];  // broadcast
        bool s0 = (i < ib);                   // wave-uniform select
        #pragma unroll
        for (int k8 = 0; k8 < 4; k8++) {
          float wgt = (s0 ? a0[k8] : a1[k8]) * eB[k8][i];
          accv[k8][0] = fmaf(wgt, v.x, accv[k8][0]);
          accv[k8][1] = fmaf(wgt, v.y, accv[k8][1]);
          accv[k8][2] = fmaf(wgt, v.z, accv[k8][2]);
          accv[k8][3] = fmaf(wgt, v.w, accv[k8][3]);
          zz[k8] += wgt;
        }
      }
    }
  }
  // ---- epilogue: per k8 group (32 rows), cross-wave reduce + partial write --
  float* sU = sB + OFF_EA;    // eA dead; 2560 <= 3072
  #pragma unroll
  for (int k8 = 0; k8 < 4; k8++) {
    __syncthreads();
    {
      float* rp = sU + (w * 64 + lane) * 5;   // stride-5: conflict-free b32
      rp[0] = accv[k8][0]; rp[1] = accv[k8][1];
      rp[2] = accv[k8][2]; rp[3] = accv[k8][3];
      rp[4] = zz[k8];
    }
    __syncthreads();
    if (tid < 256) {
      int row32 = tid & 31, c = tid >> 5;     // c 0..7
      int ln = ((c >> 2) << 5) + row32;       // chalf group holding channel c
      float num = 0.f;
      #pragma unroll
      for (int ww = 0; ww < 8; ww++) num += sU[(ww * 64 + ln) * 5 + (c & 3)];
      Pnum[((jh * 16 + bh) * 8 + c) * HW + r0 + k8 * 32 + row32] = num;
    } else if (tid < 288) {
      int row32 = tid & 31;                   // Z double-counted -> x0.5
      float z = 0.f;
      #pragma unroll
      for (int ww = 0; ww < 8; ww++)
        z += sU[(ww * 64 + row32) * 5 + 4] + sU[(ww * 64 + 32 + row32) * 5 + 4];
      PZ[(jh * 16 + bh) * HW + r0 + k8 * 32 + row32] = z * 0.5f;
    }
  }
}

// ---------------- Kernel E: combine 2 j-halves + normalize ------------------
__global__ __launch_bounds__(256) void combine_kernel(
    const float* __restrict__ Pnum, const float* __restrict__ PZ,
    float* __restrict__ out) {
  int t = blockIdx.x * 256 + threadIdx.x;   // 294912
  int row = t % HW;
  int rc = t / HW;        // bh*8 + c
  int c = rc & 7, bh = rc >> 3;
  float num = Pnum[((bh) * 8 + c) * HW + row]
            + Pnum[((16 + bh) * 8 + c) * HW + row];
  float z = PZ[bh * HW + row] + PZ[(16 + bh) * HW + row];
  int b = bh >> 3, h = bh & 7;
  out[(b * 64 + h * 8 + c) * HW + row] = num / z;
}

extern "C" void kernel_launch(void* const* d_in, const int* in_sizes, int n_in,
                              void* d_out, int out_size, void* d_ws, size_t ws_size,
                              hipStream_t stream) {
  const float* F    = (const float*)d_in[0];
  const float* Wqkv = (const float*)d_in[1];
  const float* Wq   = (const float*)d_in[2];
  const float* Bq   = (const float*)d_in[3];
  const float* Wk   = (const float*)d_in[4];
  const float* Bk   = (const float*)d_in[5];
  const float* PH   = (const float*)d_in[6];
  const float* PW   = (const float*)d_in[7];
  float* out = (float*)d_out;

  float* ws   = (float*)d_ws;
  float* QKV  = ws;                        // 884736 f
  float* V2   = QKV + 2 * HW * O192;       // 294912 f
  float* QD   = V2 + 2 * 8 * HW * 8;       // 9216 f
  float* Pnum = QD + 2 * 2 * 64 * 36;      // 2*16*8*2304 = 589824 f
  float* PZ   = Pnum + 2 * 16 * 8 * HW;    // 2*16*2304   = 73728 f

  qkv_kernel    <<<1152, 256, 0, stream>>>(F, Wqkv, QKV, V2);
  conv_kernel   <<<1536, 256, 0, stream>>>(QKV, Wq, Bq, Wk, Bk, QD);
  attn_kernel   <<<576,  512, 0, stream>>>(QKV, V2, QD, PH, PW, Pnum, PZ);
  combine_kernel<<<1152, 256, 0, stream>>>(Pnum, PZ, out);
}